// Round 4
// baseline (151.360 us; speedup 1.0000x reference)
//
#include <hip/hip_runtime.h>
#include <hip/hip_cooperative_groups.h>

#define NUM_CLASSES 4096
#define EMB_DIM 512
#define NTOK (16 * 8192)                 // 131072 tokens
#define NTILES ((NUM_CLASSES / 64) * (EMB_DIM / 64))  // 512

typedef float f32x4 __attribute__((ext_vector_type(4)));

__device__ __forceinline__ unsigned int f2bf_rn(float f) {
    unsigned int u = __float_as_uint(f);
    u += 0x7fffu + ((u >> 16) & 1u);      // round-to-nearest-even
    return u >> 16;
}

// ---------------- fused cooperative kernel ----------------
// Phase 1 (grid-stride over 512 tiles): Wtb[c][e] = bf16(W[e][c] + b[e]).
// grid.sync().
// Phase 2: per wave-iteration, one token: 2x8B contiguous table reads
// (L2-hot, 4 MiB bf16 table) -> 2x16B contiguous nontemporal stores.
__global__ void __launch_bounds__(256, 4)
fused_embed_kernel(const int* __restrict__ x,
                   const float* __restrict__ W,
                   const float* __restrict__ b,
                   unsigned int* __restrict__ Wtb2,   // 2 bf16 per uint
                   f32x4* __restrict__ out4) {
    __shared__ float tile[64][65];
    const int t  = threadIdx.x;
    const int tx = t & 63;
    const int ty = t >> 6;                // 0..3

    for (int tid = blockIdx.x; tid < NTILES; tid += gridDim.x) {
        const int c0 = (tid & 63) * 64;   // class-tile origin
        const int e0 = (tid >> 6) * 64;   // emb-tile origin
        __syncthreads();                  // protect tile reuse across iters
#pragma unroll
        for (int j = 0; j < 16; ++j)
            tile[ty + j * 4][tx] =
                W[(size_t)(e0 + ty + j * 4) * NUM_CLASSES + c0 + tx];
        __syncthreads();

        const int up = t & 31;            // e-pair index 0..31
        const int r0 = t >> 5;            // 0..7
        const int e  = 2 * up;
        const float b0 = b[e0 + e], b1 = b[e0 + e + 1];
#pragma unroll
        for (int k = 0; k < 8; ++k) {
            const int r = r0 + k * 8;     // banks: (2*up + r) % 32, 2-way = free
            const unsigned int packed =
                f2bf_rn(tile[e][r] + b0) | (f2bf_rn(tile[e + 1][r] + b1) << 16);
            Wtb2[((size_t)(c0 + r) * EMB_DIM + e0 + e) >> 1] = packed;
        }
    }

    cooperative_groups::this_grid().sync();

    // ---- gather ----
    const uint2* __restrict__ Wtb4 = (const uint2*)Wtb2;  // 4 bf16 per uint2
    const int lane = threadIdx.x & 63;
    const int wid  = blockIdx.x * 4 + (threadIdx.x >> 6);
    const int nw   = gridDim.x * 4;
    for (int p = wid; p < NTOK / 2; p += nw) {
#pragma unroll
        for (int u = 0; u < 2; ++u) {                     // ILP = 2 tokens
            const int tok = __builtin_amdgcn_readfirstlane(p * 2 + u);
            const int c   = x[tok];                       // s_load (uniform)
            const uint2 ra = Wtb4[(c << 7) | lane];       // bytes [0,512)
            const uint2 rb = Wtb4[(c << 7) | 64 | lane];  // bytes [512,1024)
            f32x4 va, vb;
            va.x = __uint_as_float(ra.x << 16);
            va.y = __uint_as_float(ra.x & 0xffff0000u);
            va.z = __uint_as_float(ra.y << 16);
            va.w = __uint_as_float(ra.y & 0xffff0000u);
            vb.x = __uint_as_float(rb.x << 16);
            vb.y = __uint_as_float(rb.x & 0xffff0000u);
            vb.z = __uint_as_float(rb.y << 16);
            vb.w = __uint_as_float(rb.y & 0xffff0000u);
            __builtin_nontemporal_store(va, &out4[(tok << 7) | lane]);
            __builtin_nontemporal_store(vb, &out4[(tok << 7) | 64 | lane]);
        }
    }
}

// ---------------- fallback: proven R3 two-kernel path ----------------
__global__ void __launch_bounds__(1024)
transpose_bias_bf16_kernel(const float* __restrict__ W,
                           const float* __restrict__ b,
                           unsigned int* __restrict__ Wtb2) {
    __shared__ float tile[64][65];
    const int c0 = blockIdx.x * 64;
    const int e0 = blockIdx.y * 64;
    const int tx = threadIdx.x;
    const int ty = threadIdx.y;
#pragma unroll
    for (int j = 0; j < 64; j += 16)
        tile[ty + j][tx] = W[(size_t)(e0 + ty + j) * NUM_CLASSES + (c0 + tx)];
    __syncthreads();
    const int t  = ty * 64 + tx;
    const int ep = t & 31;
    const int r0 = t >> 5;
#pragma unroll
    for (int p = 0; p < 2; ++p) {
        const int r = r0 + p * 32;
        const int e = 2 * ep;
        const float v0 = tile[e][r]     + b[e0 + e];
        const float v1 = tile[e + 1][r] + b[e0 + e + 1];
        Wtb2[((size_t)(c0 + r) * EMB_DIM + e0 + e) >> 1] =
            f2bf_rn(v0) | (f2bf_rn(v1) << 16);
    }
}

__global__ void __launch_bounds__(256)
gather_bf16_kernel(const int* __restrict__ x,
                   const uint2* __restrict__ Wtb4,
                   f32x4* __restrict__ out4) {
    const int base = blockIdx.x * 1024 + threadIdx.x;
#pragma unroll
    for (int k = 0; k < 4; ++k) {
        const int g   = base + k * 256;
        const int tok = __builtin_amdgcn_readfirstlane(g >> 7);
        const int c   = x[tok];
        const uint2 raw = Wtb4[(c << 7) | (g & 127)];
        f32x4 v;
        v.x = __uint_as_float(raw.x << 16);
        v.y = __uint_as_float(raw.x & 0xffff0000u);
        v.z = __uint_as_float(raw.y << 16);
        v.w = __uint_as_float(raw.y & 0xffff0000u);
        __builtin_nontemporal_store(v, &out4[g]);
    }
}

__global__ void __launch_bounds__(256)
direct_kernel(const int* __restrict__ x,
              const float* __restrict__ W,
              const float* __restrict__ b,
              float* __restrict__ out,
              long long total) {
    const long long stride = (long long)gridDim.x * blockDim.x;
    for (long long g = (long long)blockIdx.x * blockDim.x + threadIdx.x;
         g < total; g += stride) {
        const int tok = (int)(g >> 9);
        const int e   = (int)(g & (EMB_DIM - 1));
        out[g] = W[(size_t)e * NUM_CLASSES + x[tok]] + b[e];
    }
}

extern "C" void kernel_launch(void* const* d_in, const int* in_sizes, int n_in,
                              void* d_out, int out_size, void* d_ws, size_t ws_size,
                              hipStream_t stream) {
    const int*   x = (const int*)d_in[0];    // [16, 8192]
    const float* W = (const float*)d_in[1];  // [512, 4096]
    const float* b = (const float*)d_in[2];  // [512]

    const long long total  = (long long)out_size;           // 67,108,864
    const size_t wtb_bytes = (size_t)NUM_CLASSES * EMB_DIM * 2;  // 4 MiB

    if (ws_size < wtb_bytes) {
        direct_kernel<<<4096, 256, 0, stream>>>(x, W, b, (float*)d_out, total);
        return;
    }

    unsigned int* Wtb = (unsigned int*)d_ws;
    f32x4* out4 = (f32x4*)d_out;

    // Size cooperative grid to guaranteed co-residency.
    int perCU = 0;
    hipError_t oerr = hipOccupancyMaxActiveBlocksPerMultiprocessor(
        &perCU, (const void*)fused_embed_kernel, 256, 0);
    int grid = (oerr == hipSuccess && perCU > 0)
                   ? (perCU > 8 ? 8 : perCU) * 256   // 256 CUs on MI355X
                   : 0;
    if (grid > 2048) grid = 2048;

    bool launched = false;
    if (grid >= 256) {
        void* args[] = {(void*)&x, (void*)&W, (void*)&b, (void*)&Wtb, (void*)&out4};
        hipError_t lerr = hipLaunchCooperativeKernel(
            (const void*)fused_embed_kernel, dim3(grid), dim3(256), args, 0, stream);
        launched = (lerr == hipSuccess);
    }

    if (!launched) {
        dim3 tb(64, 16);
        dim3 tg(NUM_CLASSES / 64, EMB_DIM / 64);
        transpose_bias_bf16_kernel<<<tg, tb, 0, stream>>>(W, b, Wtb);
        gather_bf16_kernel<<<16384, 256, 0, stream>>>(x, (const uint2*)Wtb, out4);
    }
}

// Round 5
// 55.878 us; speedup vs baseline: 2.7087x; 2.7087x over previous
//
#include <hip/hip_runtime.h>

#define NUM_CLASSES 4096
#define EMB_DIM 512

typedef float f32x4 __attribute__((ext_vector_type(4)));

__device__ __forceinline__ unsigned int f2bf_rn(float f) {
    unsigned int u = __float_as_uint(f);
    u += 0x7fffu + ((u >> 16) & 1u);      // round-to-nearest-even
    return u >> 16;
}

// Kernel 1: Wtb[c][e] = bf16_rn(W[e][c] + b[e])
// W: [EMB_DIM][NUM_CLASSES] f32 row-major -> Wtb: [NUM_CLASSES][EMB_DIM] bf16.
// 4 MiB result == one XCD's L2, so the gather reads stay L2-resident.
__global__ void __launch_bounds__(1024)
transpose_bias_bf16_kernel(const float* __restrict__ W,
                           const float* __restrict__ b,
                           unsigned int* __restrict__ Wtb2) {  // 2 bf16 per uint
    __shared__ float tile[64][65];       // [e_local][c_local], +1 pad
    const int c0 = blockIdx.x * 64;
    const int e0 = blockIdx.y * 64;
    const int tx = threadIdx.x;          // 0..63
    const int ty = threadIdx.y;          // 0..15

#pragma unroll
    for (int j = 0; j < 64; j += 16)
        tile[ty + j][tx] = W[(size_t)(e0 + ty + j) * NUM_CLASSES + (c0 + tx)];
    __syncthreads();

    const int t  = ty * 64 + tx;         // 0..1023
    const int ep = t & 31;               // e-pair index 0..31
    const int r0 = t >> 5;               // class row 0..31
#pragma unroll
    for (int p = 0; p < 2; ++p) {
        const int r = r0 + p * 32;
        const int e = 2 * ep;
        const float v0 = tile[e][r]     + b[e0 + e];
        const float v1 = tile[e + 1][r] + b[e0 + e + 1];
        Wtb2[((size_t)(c0 + r) * EMB_DIM + e0 + e) >> 1] =
            f2bf_rn(v0) | (f2bf_rn(v1) << 16);
    }
}

// Kernel 2: out[t][e] = f32(Wtb[x[t]][e]).
// 16384 blocks x 256 threads, 4 independent float4 per thread: maximal
// inter-wave MLP, no loop-carried state. Token id is wave-uniform ->
// readfirstlane makes x[] a scalar load. 8 B L2-hot table read + 16 B
// nontemporal store per lane-iteration, both unit-stride within the wave.
__global__ void __launch_bounds__(256)
gather_bf16_kernel(const int* __restrict__ x,
                   const uint2* __restrict__ Wtb4,   // 4 bf16 per uint2
                   f32x4* __restrict__ out4) {
    const int base = blockIdx.x * 1024 + threadIdx.x;   // float4 index, ILP=4
#pragma unroll
    for (int k = 0; k < 4; ++k) {
        const int g   = base + k * 256;
        const int tok = __builtin_amdgcn_readfirstlane(g >> 7);  // wave-uniform
        const int c   = x[tok];                                  // s_load
        const uint2 raw = Wtb4[(c << 7) | (g & 127)];
        f32x4 v;
        v.x = __uint_as_float(raw.x << 16);
        v.y = __uint_as_float(raw.x & 0xffff0000u);
        v.z = __uint_as_float(raw.y << 16);
        v.w = __uint_as_float(raw.y & 0xffff0000u);
        __builtin_nontemporal_store(v, &out4[g]);
    }
}

// Fallback (only if ws too small): direct strided gather, still correct.
__global__ void __launch_bounds__(256)
direct_kernel(const int* __restrict__ x,
              const float* __restrict__ W,
              const float* __restrict__ b,
              float* __restrict__ out,
              long long total) {
    const long long stride = (long long)gridDim.x * blockDim.x;
    for (long long g = (long long)blockIdx.x * blockDim.x + threadIdx.x;
         g < total; g += stride) {
        const int tok = (int)(g >> 9);
        const int e   = (int)(g & (EMB_DIM - 1));
        out[g] = W[(size_t)e * NUM_CLASSES + x[tok]] + b[e];
    }
}

extern "C" void kernel_launch(void* const* d_in, const int* in_sizes, int n_in,
                              void* d_out, int out_size, void* d_ws, size_t ws_size,
                              hipStream_t stream) {
    const int*   x = (const int*)d_in[0];    // [16, 8192] class ids
    const float* W = (const float*)d_in[1];  // [512, 4096]
    const float* b = (const float*)d_in[2];  // [512]

    const long long total  = (long long)out_size;   // 67,108,864
    const size_t wtb_bytes = (size_t)NUM_CLASSES * EMB_DIM * 2;  // 4 MiB bf16

    if (ws_size >= wtb_bytes) {
        unsigned int* Wtb = (unsigned int*)d_ws;
        dim3 tb(64, 16);
        dim3 tg(NUM_CLASSES / 64, EMB_DIM / 64);    // 64 x 8 blocks
        transpose_bias_bf16_kernel<<<tg, tb, 0, stream>>>(W, b, Wtb);

        // total4 = 16,777,216 float4; 1024 float4/block -> exact 16384 blocks
        gather_bf16_kernel<<<16384, 256, 0, stream>>>(
            x, (const uint2*)Wtb, (f32x4*)d_out);
    } else {
        direct_kernel<<<4096, 256, 0, stream>>>(x, W, b, (float*)d_out, total);
    }
}